// Round 11
// baseline (528.633 us; speedup 1.0000x reference)
//
#include <hip/hip_runtime.h>

#define TT    512
#define HH    64
#define NB    2      // batches per block (cols 0-1 real; 2-3 zero-input, finite)
#define NBLK  512    // 2 independent 8-wave blocks per CU
#define HP    72     // h^T pitch in f16

#define LOG2E 1.44269504f

typedef _Float16 f16x8 __attribute__((ext_vector_type(8)));
typedef _Float16 f16x4 __attribute__((ext_vector_type(4)));
typedef float    f32x4 __attribute__((ext_vector_type(4)));

#if __has_builtin(__builtin_amdgcn_exp2f)
#define EXP2(x) __builtin_amdgcn_exp2f(x)
#else
#define EXP2(x) exp2f(x)
#endif

// r20 = r19's arithmetic (exp2/sign folding + rcp pointwise + 4-deep C chain)
// restructured for 2-blocks/CU co-residency with THIN waves:
//  - Per-group tick loops (wave-uniform branch; BOTH paths execute exactly
//    513 barriers via raw "s_waitcnt lgkmcnt(0); s_barrier") so A's frags
//    (whh0/axf/bias) and C's frags (wih1/whh1/bias) are never live on the
//    same path. r12/r19's single-loop form kept the UNION live (~96
//    persistent VGPR + acc -> ~200 total -> 2 waves/SIMD -> a second block
//    never co-resided; r12's exact-2x serialization).
//  - __launch_bounds__(512,4): 4 waves/SIMD -> cap 128 regs/wave total.
//  - NB=2, NBLK=512: two INDEPENDENT blocks per CU at different phases fill
//    each other's LDS-latency/barrier stalls (r15 evidence: independent
//    co-resident blocks raised MfmaUtil 22->32.6 even at 2 waves/SIMD; it
//    lost only on fat-wave issue+spill, which thin waves avoid).
// Per-batch arithmetic identical to r19 (passed, absmax 3.9e-3): folding
// scales rows pre-f16-cast; batch cols 2-3 run the zero-input LSTM (finite,
// never stored). xs layout = r9's [t][d][4] with b>=NB zero-filled (r11
// lesson: never reshape xs).
// LESSONS: r8 cross-block 4x. r10 16-lane pointwise 2x. r13 fat 2-wave
// 2.2x. r14 chain cuts neutral. r15 fat+spill. r16 spin-barriers worse.
// r17 rcp -19%. r18 C-split regression. r19 folding: VALU down, wall flat
// -> stall-bound; this round targets the stall.
__device__ __forceinline__ float sig2_(float xs) {   // xs = -x*log2e (pre-folded)
    return __builtin_amdgcn_rcpf(1.0f + EXP2(xs));
}
__device__ __forceinline__ float tanh2_(float xs) {  // xs = 2x*log2e (pre-folded)
    return 1.0f - 2.0f * __builtin_amdgcn_rcpf(1.0f + EXP2(xs));
}

__device__ __forceinline__ void tick_barrier() {
    asm volatile("s_waitcnt lgkmcnt(0)\n\ts_barrier" ::: "memory");
}

__global__ __launch_bounds__(512, 4) void lstm_mfma(
    const float* __restrict__ x,
    const float* __restrict__ w_ih0, const float* __restrict__ w_hh0,
    const float* __restrict__ b_ih0, const float* __restrict__ b_hh0,
    const float* __restrict__ w_ih1, const float* __restrict__ w_hh1,
    const float* __restrict__ b_ih1, const float* __restrict__ b_hh1,
    const float* __restrict__ w_out, const float* __restrict__ b_out,
    float* __restrict__ out)
{
    __shared__ __align__(16) _Float16 h1T[2][16 * HP];  // h1^T [batch][unit] f16
    __shared__ __align__(16) _Float16 h2T[2][16 * HP];  // h2^T
    __shared__ float xs[TT * 12];                       // x [t][d][4] fp32 (r9 layout)
    __shared__ __align__(16) f32x4 cellA[4][64];        // A gate transpose
    __shared__ __align__(16) f32x4 cellC[4][64];        // C gate transpose
    __shared__ __align__(16) float h2f[16 * 68];        // final h2 fp32
    __shared__ float lg[4][4];

    const int tid   = threadIdx.x;
    const int group = tid >> 8;          // 0 = A (layer 1), 1 = C (layer 2)
    const int w     = (tid >> 6) & 3;    // wave-in-group
    const int lane  = tid & 63;
    const int quad  = lane >> 4;
    const int n     = lane & 15;         // MFMA column = batch slot
    const int b0    = blockIdx.x * NB;

    const int cu    = lane >> 2;                      // unit after transpose
    const int cb    = lane & 3;                       // batch after transpose
    const int rdslot = lane ^ ((lane >> 4) << 2);     // XOR-swizzled cell slot

    // ---- LDS init (all 512 threads) ----
    for (int i = tid; i < 1152; i += 512) {
        ((int*)h1T)[i] = 0;
        ((int*)h2T)[i] = 0;
    }
    for (int i = tid; i < TT * 12; i += 512) {
        const int t = i / 12, rem = i - t * 12;
        const int d = rem >> 2, b = rem & 3;          // only b<NB real
        xs[i] = (b < NB) ? x[(size_t)(b0 + b) * (TT * 3) + t * 3 + d] : 0.f;
    }
    __syncthreads();

    if (group == 0) {
        // =============== group A : layer 1 (own frags only) ===============
        f16x8 whh[4][2], axf[4];
        f32x4 biasf[4];
        #pragma unroll
        for (int g_ = 0; g_ < 4; ++g_) {
            const float sc = (g_ == 2) ? (2.0f * LOG2E) : (-LOG2E);
            const int arow = 16 * w + 64 * g_ + n;
            const float* ph = w_hh0 + arow * HH;
            #pragma unroll
            for (int k0 = 0; k0 < 2; ++k0)
                #pragma unroll
                for (int j = 0; j < 8; ++j)
                    whh[g_][k0][j] = (_Float16)(sc * ph[quad * 8 + 32 * k0 + j]);
            #pragma unroll
            for (int r = 0; r < 4; ++r) {
                const int crow = 16 * w + 64 * g_ + quad * 4 + r;
                biasf[g_][r] = sc * (b_ih0[crow] + b_hh0[crow]);
            }
            f16x8 ax;
            #pragma unroll
            for (int j = 0; j < 8; ++j) ax[j] = (_Float16)0.f;
            if (quad == 0) {
                ax[0] = (_Float16)(sc * w_ih0[arow * 3 + 0]);
                ax[1] = (_Float16)(sc * w_ih0[arow * 3 + 1]);
                ax[2] = (_Float16)(sc * w_ih0[arow * 3 + 2]);
            }
            axf[g_] = ax;
        }
        float creg = 0.f;

        for (int t = 0; t <= TT; ++t) {
            if (t < TT) {
                f16x8 bx;
                #pragma unroll
                for (int j = 0; j < 8; ++j) bx[j] = (_Float16)0.f;
                if (quad == 0) {
                    const float* xp = xs + t * 12 + (lane & 3);
                    bx[0] = (_Float16)xp[0];
                    bx[1] = (_Float16)xp[4];
                    bx[2] = (_Float16)xp[8];
                }
                const _Float16* hsrc = h1T[(t + 1) & 1];
                const f16x8 bh0 = *(const f16x8*)(hsrc + n * HP + quad * 8);
                const f16x8 bh1 = *(const f16x8*)(hsrc + n * HP + quad * 8 + 32);
                f32x4 acc[4];
                #pragma unroll
                for (int g_ = 0; g_ < 4; ++g_) {
                    f32x4 a = __builtin_amdgcn_mfma_f32_16x16x32_f16(axf[g_], bx, biasf[g_], 0, 0, 0);
                    a = __builtin_amdgcn_mfma_f32_16x16x32_f16(whh[g_][0], bh0, a, 0, 0, 0);
                    a = __builtin_amdgcn_mfma_f32_16x16x32_f16(whh[g_][1], bh1, a, 0, 0, 0);
                    acc[g_] = a;
                }
                if (n < 4) {
                    #pragma unroll
                    for (int r = 0; r < 4; ++r) {
                        const int slot = (16 * quad + 4 * r + n) ^ (quad << 2);
                        f32x4 v = {acc[0][r], acc[1][r], acc[2][r], acc[3][r]};
                        cellA[w][slot] = v;
                    }
                }
                const f32x4 gate = cellA[w][rdslot];
                const float is = sig2_(gate[0]);
                const float fs = sig2_(gate[1]);
                const float gt = tanh2_(gate[2]);
                const float os = sig2_(gate[3]);
                creg = fs * creg + is * gt;
                h1T[t & 1][cb * HP + 16 * w + cu] =
                    (_Float16)(os * tanh2_(creg * (2.0f * LOG2E)));
            }
            tick_barrier();
        }
    } else {
        // =============== group C : layer 2 (own frags only) ===============
        f16x8 wih[4][2], whh[4][2];
        f32x4 biasf[4];
        #pragma unroll
        for (int g_ = 0; g_ < 4; ++g_) {
            const float sc = (g_ == 2) ? (2.0f * LOG2E) : (-LOG2E);
            const int arow = 16 * w + 64 * g_ + n;
            const float* pi = w_ih1 + arow * HH;
            const float* ph = w_hh1 + arow * HH;
            #pragma unroll
            for (int k0 = 0; k0 < 2; ++k0)
                #pragma unroll
                for (int j = 0; j < 8; ++j) {
                    wih[g_][k0][j] = (_Float16)(sc * pi[quad * 8 + 32 * k0 + j]);
                    whh[g_][k0][j] = (_Float16)(sc * ph[quad * 8 + 32 * k0 + j]);
                }
            #pragma unroll
            for (int r = 0; r < 4; ++r) {
                const int crow = 16 * w + 64 * g_ + quad * 4 + r;
                biasf[g_][r] = sc * (b_ih1[crow] + b_hh1[crow]);
            }
        }
        float creg = 0.f;

        for (int t = 0; t <= TT; ++t) {
            if (t >= 1) {
                const _Float16* h1src = h1T[(t + 1) & 1];
                const _Float16* h2src = h2T[(t + 1) & 1];
                const f16x8 b10 = *(const f16x8*)(h1src + n * HP + quad * 8);
                const f16x8 b11 = *(const f16x8*)(h1src + n * HP + quad * 8 + 32);
                const f16x8 b20 = *(const f16x8*)(h2src + n * HP + quad * 8);
                const f16x8 b21 = *(const f16x8*)(h2src + n * HP + quad * 8 + 32);
                f32x4 acc[4];
                #pragma unroll
                for (int g_ = 0; g_ < 4; ++g_) {
                    f32x4 a = __builtin_amdgcn_mfma_f32_16x16x32_f16(wih[g_][0], b10, biasf[g_], 0, 0, 0);
                    a = __builtin_amdgcn_mfma_f32_16x16x32_f16(wih[g_][1], b11, a, 0, 0, 0);
                    a = __builtin_amdgcn_mfma_f32_16x16x32_f16(whh[g_][0], b20, a, 0, 0, 0);
                    a = __builtin_amdgcn_mfma_f32_16x16x32_f16(whh[g_][1], b21, a, 0, 0, 0);
                    acc[g_] = a;
                }
                if (n < 4) {
                    #pragma unroll
                    for (int r = 0; r < 4; ++r) {
                        const int slot = (16 * quad + 4 * r + n) ^ (quad << 2);
                        f32x4 v = {acc[0][r], acc[1][r], acc[2][r], acc[3][r]};
                        cellC[w][slot] = v;
                    }
                }
                const f32x4 gate = cellC[w][rdslot];
                const float is = sig2_(gate[0]);
                const float fs = sig2_(gate[1]);
                const float gt = tanh2_(gate[2]);
                const float os = sig2_(gate[3]);
                creg = fs * creg + is * gt;
                const float h = os * tanh2_(creg * (2.0f * LOG2E));
                h2T[t & 1][cb * HP + 16 * w + cu] = (_Float16)h;   // h2(t-1)
                if (t == TT) h2f[cb * 68 + 16 * w + cu] = h;       // h2(TT-1) fp32
            }
            tick_barrier();
        }
    }
    __syncthreads();

    // ---- epilogue: logits + softmax on fp32 h2 ----
    if (tid < 16) {
        const int b = tid & 3, o = tid >> 2;
        float acc = b_out[o];
        #pragma unroll
        for (int j = 0; j < HH; ++j)
            acc = fmaf(w_out[o * HH + j], h2f[b * 68 + j], acc);
        lg[b][o] = acc;
    }
    __syncthreads();
    if (tid < NB) {
        const int b = tid;
        const float l0 = lg[b][0], l1 = lg[b][1], l2 = lg[b][2], l3 = lg[b][3];
        const float m  = fmaxf(fmaxf(l0, l1), fmaxf(l2, l3));
        const float e0 = __expf(l0 - m), e1 = __expf(l1 - m);
        const float e2 = __expf(l2 - m), e3 = __expf(l3 - m);
        const float sum = 1.0f / (e0 + e1 + e2 + e3);
        out[(b0 + b) * 4 + 0] = e0 * sum;
        out[(b0 + b) * 4 + 1] = e1 * sum;
        out[(b0 + b) * 4 + 2] = e2 * sum;
        out[(b0 + b) * 4 + 3] = e3 * sum;
    }
}

extern "C" void kernel_launch(void* const* d_in, const int* in_sizes, int n_in,
                              void* d_out, int out_size, void* d_ws, size_t ws_size,
                              hipStream_t stream) {
    const float* x     = (const float*)d_in[0];
    const float* w_ih0 = (const float*)d_in[1];
    const float* w_hh0 = (const float*)d_in[2];
    const float* b_ih0 = (const float*)d_in[3];
    const float* b_hh0 = (const float*)d_in[4];
    const float* w_ih1 = (const float*)d_in[5];
    const float* w_hh1 = (const float*)d_in[6];
    const float* b_ih1 = (const float*)d_in[7];
    const float* b_hh1 = (const float*)d_in[8];
    const float* w_out = (const float*)d_in[9];
    const float* b_out = (const float*)d_in[10];
    float* out = (float*)d_out;

    hipLaunchKernelGGL(lstm_mfma, dim3(NBLK), dim3(512), 0, stream,
                       x, w_ih0, w_hh0, b_ih0, b_hh0,
                       w_ih1, w_hh1, b_ih1, b_hh1,
                       w_out, b_out, out);
}

// Round 12
// 301.708 us; speedup vs baseline: 1.7521x; 1.7521x over previous
//
#include <hip/hip_runtime.h>

#define TT    512
#define HH    64
#define NB    4
#define NBLK  256
#define HP    80    // h^T batch pitch in f16: 160B -> dword stride 40 == 8 mod 32
                    // -> the 16 distinct (batch,quad) 16B chunks are exactly 2-way
                    // per bank group, which is free (m136). HP=72 was 4-way-ish.

#define LOG2E 1.44269504f

typedef _Float16 f16x8 __attribute__((ext_vector_type(8)));
typedef float    f32x4 __attribute__((ext_vector_type(4)));

#if __has_builtin(__builtin_amdgcn_exp2f)
#define EXP2(x) __builtin_amdgcn_exp2f(x)
#else
#define EXP2(x) exp2f(x)
#endif

// r21: SWAPPED-OPERAND MFMA kills the cell-transpose LDS round trip.
//   D = A.B with A = h^T (batch-replicated rows: A-row m carries batch m>>2)
//   and B = W^T (B-col n = weight row 64g+16w+n; SAME load expressions as the
//   old A=W frags). C/D: col=lane&15, row=4*quad+reg -> D-row 4q+r = batch
//   (4q+r)>>2 = quad for EVERY reg -> lane (n,quad) holds the gate value of
//   (gate-tile g, unit 16w+n, batch quad) in all 4 acc components. Tiles =
//   gates -> each lane owns ONE cell's i,f,g,o in acc[0..3][0]: pointwise on
//   all 64 lanes (r10 lesson), ZERO post-MFMA data movement. Same products,
//   same k-order -> bitwise identical to r19 (absmax 0.00390625).
//   h reads become 4-lane broadcasts (16 distinct chunks); cellA/cellC LDS
//   deleted -> bank conflicts (~128 cy/tick, 1.68e7/dispatch) mostly gone.
// Carries r17's rcp pointwise + r18/r19's exp2/sign weight folding.
// 256 blocks x 512 threads, 1 block/CU. Group A = waves 0-3 (layer 1),
// group C = waves 4-7 (layer 2, fused K=128 over [h1;h2], 4-deep chain).
// One __syncthreads per tick.
// LESSONS: r8 cross-block 4x. r10 16-lane pointwise 2x. r12/r20 co-residency
// cannot shorten the sequential chain (wall = ticks x tick-latency). r13/r15
// fat waves spill. r14 chain cuts neutral pre-r17. r16 spin-barriers worse.
// r17 rcp -19%. r18 C-split regression. r19 folding: VALU down, wall flat.
__device__ __forceinline__ float sig2_(float xs) {   // xs = -x*log2e (pre-folded)
    return __builtin_amdgcn_rcpf(1.0f + EXP2(xs));
}
__device__ __forceinline__ float tanh2_(float xs) {  // xs = 2x*log2e (pre-folded)
    return 1.0f - 2.0f * __builtin_amdgcn_rcpf(1.0f + EXP2(xs));
}

__global__ __launch_bounds__(512) void lstm_mfma(
    const float* __restrict__ x,
    const float* __restrict__ w_ih0, const float* __restrict__ w_hh0,
    const float* __restrict__ b_ih0, const float* __restrict__ b_hh0,
    const float* __restrict__ w_ih1, const float* __restrict__ w_hh1,
    const float* __restrict__ b_ih1, const float* __restrict__ b_hh1,
    const float* __restrict__ w_out, const float* __restrict__ b_out,
    float* __restrict__ out)
{
    __shared__ __align__(16) _Float16 h1T[2][4 * HP];   // h1 [batch][unit] f16
    __shared__ __align__(16) _Float16 h2T[2][4 * HP];   // h2 [batch][unit] f16
    __shared__ float xs[TT * 12];                       // x [t][d][4] fp32
    __shared__ __align__(16) float h2f[4 * 68];         // final h2 fp32
    __shared__ float lg[NB][4];

    const int tid   = threadIdx.x;
    const int group = tid >> 8;          // 0 = A (layer 1), 1 = C (layer 2)
    const int w     = (tid >> 6) & 3;    // wave-in-group
    const int lane  = tid & 63;
    const int quad  = lane >> 4;
    const int n     = lane & 15;         // B-col = gate-row-in-tile; also A-row idx
    const int bq    = n >> 2;            // batch carried by this lane's A-row
    const int b0    = blockIdx.x * NB;

    // ---- persistent weight fragments (B-operand = W^T; identical load
    //      expressions to the old A=W frags). Gate-scaled: i,f,o x-log2e,
    //      g x2log2e (r18 folding). Bias is per-B-col -> uniform in reg r. ----
    f16x8 whh[4][2], wih[4][2], axf[4];
    f32x4 biasf[4];
    #pragma unroll
    for (int g_ = 0; g_ < 4; ++g_) {
        const float sc = (g_ == 2) ? (2.0f * LOG2E) : (-LOG2E);
        const int arow = 16 * w + 64 * g_ + n;        // weight row of B-col n
        const float* ph = (group == 0) ? (w_hh0 + arow * HH) : (w_hh1 + arow * HH);
        const float* pi = w_ih1 + arow * HH;
        #pragma unroll
        for (int k0 = 0; k0 < 2; ++k0) {
            #pragma unroll
            for (int j = 0; j < 8; ++j) {
                whh[g_][k0][j] = (_Float16)(sc * ph[quad * 8 + 32 * k0 + j]);
                wih[g_][k0][j] = (group == 1) ? (_Float16)(sc * pi[quad * 8 + 32 * k0 + j])
                                              : (_Float16)0.f;
            }
        }
        const float bv = sc * ((group == 0) ? (b_ih0[arow] + b_hh0[arow])
                                            : (b_ih1[arow] + b_hh1[arow]));
        #pragma unroll
        for (int r = 0; r < 4; ++r) biasf[g_][r] = bv;
        f16x8 ax;
        #pragma unroll
        for (int j = 0; j < 8; ++j) ax[j] = (_Float16)0.f;
        if (group == 0 && quad == 0) {                // K=3 x-transform (scaled)
            ax[0] = (_Float16)(sc * w_ih0[arow * 3 + 0]);
            ax[1] = (_Float16)(sc * w_ih0[arow * 3 + 1]);
            ax[2] = (_Float16)(sc * w_ih0[arow * 3 + 2]);
        }
        axf[g_] = ax;
    }

    // ---- LDS init ----
    for (int i = tid; i < 2 * 4 * HP / 2; i += 512) {   // ints: 2 bufs * 4*HP f16
        ((int*)h1T)[i] = 0;
        ((int*)h2T)[i] = 0;
    }
    for (int i = tid; i < TT * 12; i += 512) {
        const int t = i / 12, rem = i - t * 12;
        const int d = rem >> 2, b = rem & 3;
        xs[i] = x[(size_t)(b0 + b) * (TT * 3) + t * 3 + d];
    }
    __syncthreads();

    float creg = 0.f;    // cell c of (unit 16w+n, batch quad) for this group's layer

    for (int t = 0; t <= TT; ++t) {
        if (group == 0) {
            if (t < TT) {
                f16x8 bx;                              // A-operand: x, batch bq
                #pragma unroll
                for (int j = 0; j < 8; ++j) bx[j] = (_Float16)0.f;
                if (quad == 0) {
                    const float* xp = xs + t * 12 + bq;
                    bx[0] = (_Float16)xp[0];
                    bx[1] = (_Float16)xp[4];
                    bx[2] = (_Float16)xp[8];
                }
                const _Float16* hsrc = h1T[(t + 1) & 1];
                const f16x8 bh0 = *(const f16x8*)(hsrc + bq * HP + quad * 8);
                const f16x8 bh1 = *(const f16x8*)(hsrc + bq * HP + quad * 8 + 32);
                f32x4 acc[4];
                #pragma unroll
                for (int g_ = 0; g_ < 4; ++g_) {
                    f32x4 a = __builtin_amdgcn_mfma_f32_16x16x32_f16(bx, axf[g_], biasf[g_], 0, 0, 0);
                    a = __builtin_amdgcn_mfma_f32_16x16x32_f16(bh0, whh[g_][0], a, 0, 0, 0);
                    a = __builtin_amdgcn_mfma_f32_16x16x32_f16(bh1, whh[g_][1], a, 0, 0, 0);
                    acc[g_] = a;
                }
                // lane (n,quad) holds cell (unit 16w+n, batch quad): gates in acc[g][0]
                const float is = sig2_(acc[0][0]);
                const float fs = sig2_(acc[1][0]);
                const float gt = tanh2_(acc[2][0]);
                const float os = sig2_(acc[3][0]);
                creg = fs * creg + is * gt;
                h1T[t & 1][quad * HP + 16 * w + n] =
                    (_Float16)(os * tanh2_(creg * (2.0f * LOG2E)));
            }
        } else {
            if (t >= 1) {
                // fused K=128 matvec over [h1(t-1); h2(t-2)], 4-deep chain
                const _Float16* h1src = h1T[(t + 1) & 1];
                const _Float16* h2src = h2T[(t + 1) & 1];
                const f16x8 b10 = *(const f16x8*)(h1src + bq * HP + quad * 8);
                const f16x8 b11 = *(const f16x8*)(h1src + bq * HP + quad * 8 + 32);
                const f16x8 b20 = *(const f16x8*)(h2src + bq * HP + quad * 8);
                const f16x8 b21 = *(const f16x8*)(h2src + bq * HP + quad * 8 + 32);
                f32x4 acc[4];
                #pragma unroll
                for (int g_ = 0; g_ < 4; ++g_) {
                    f32x4 a = __builtin_amdgcn_mfma_f32_16x16x32_f16(b10, wih[g_][0], biasf[g_], 0, 0, 0);
                    a = __builtin_amdgcn_mfma_f32_16x16x32_f16(b11, wih[g_][1], a, 0, 0, 0);
                    a = __builtin_amdgcn_mfma_f32_16x16x32_f16(b20, whh[g_][0], a, 0, 0, 0);
                    a = __builtin_amdgcn_mfma_f32_16x16x32_f16(b21, whh[g_][1], a, 0, 0, 0);
                    acc[g_] = a;
                }
                const float is = sig2_(acc[0][0]);
                const float fs = sig2_(acc[1][0]);
                const float gt = tanh2_(acc[2][0]);
                const float os = sig2_(acc[3][0]);
                creg = fs * creg + is * gt;
                const float h = os * tanh2_(creg * (2.0f * LOG2E));
                h2T[t & 1][quad * HP + 16 * w + n] = (_Float16)h;   // h2(t-1)
                if (t == TT) h2f[quad * 68 + 16 * w + n] = h;       // h2(TT-1) fp32
            }
        }
        __syncthreads();
    }

    // ---- epilogue: logits + softmax on fp32 h2 ----
    if (tid < 16) {
        const int b = tid & 3, o = tid >> 2;
        float acc = b_out[o];
        #pragma unroll
        for (int j = 0; j < HH; ++j)
            acc = fmaf(w_out[o * HH + j], h2f[b * 68 + j], acc);
        lg[b][o] = acc;
    }
    __syncthreads();
    if (tid < NB) {
        const int b = tid;
        const float l0 = lg[b][0], l1 = lg[b][1], l2 = lg[b][2], l3 = lg[b][3];
        const float m  = fmaxf(fmaxf(l0, l1), fmaxf(l2, l3));
        const float e0 = __expf(l0 - m), e1 = __expf(l1 - m);
        const float e2 = __expf(l2 - m), e3 = __expf(l3 - m);
        const float sum = 1.0f / (e0 + e1 + e2 + e3);
        out[(b0 + b) * 4 + 0] = e0 * sum;
        out[(b0 + b) * 4 + 1] = e1 * sum;
        out[(b0 + b) * 4 + 2] = e2 * sum;
        out[(b0 + b) * 4 + 3] = e3 * sum;
    }
}

extern "C" void kernel_launch(void* const* d_in, const int* in_sizes, int n_in,
                              void* d_out, int out_size, void* d_ws, size_t ws_size,
                              hipStream_t stream) {
    const float* x     = (const float*)d_in[0];
    const float* w_ih0 = (const float*)d_in[1];
    const float* w_hh0 = (const float*)d_in[2];
    const float* b_ih0 = (const float*)d_in[3];
    const float* b_hh0 = (const float*)d_in[4];
    const float* w_ih1 = (const float*)d_in[5];
    const float* w_hh1 = (const float*)d_in[6];
    const float* b_ih1 = (const float*)d_in[7];
    const float* b_hh1 = (const float*)d_in[8];
    const float* w_out = (const float*)d_in[9];
    const float* b_out = (const float*)d_in[10];
    float* out = (float*)d_out;

    hipLaunchKernelGGL(lstm_mfma, dim3(NBLK), dim3(512), 0, stream,
                       x, w_ih0, w_hh0, b_ih0, b_hh0,
                       w_ih1, w_hh1, b_ih1, b_hh1,
                       w_out, b_out, out);
}